// Round 5
// baseline (198.310 us; speedup 1.0000x reference)
//
#include <hip/hip_runtime.h>
#include <math.h>

#define EPS 1e-8f
#define HALF_BIN 0.05f

typedef float v4f __attribute__((ext_vector_type(4)));

// Inline-asm 16B load: the HIP backend sinks C++ loads to just before use and
// emits per-use s_waitcnt (observed R2-R4: VGPR pinned at 32-44, MLP~1/wave).
// Asm loads are issued where written; we wait once per group via a single
// s_waitcnt vmcnt(0) whose tied "+v" operands order it between all loads and
// all uses.
#define GLOAD4(dst, addr) \
    asm("global_load_dwordx4 %0, %1, off" : "=v"(dst) : "v"(addr))

// pd = sigmoid(xu) - sigmoid(xl) with one reciprocal:
//   pd = (e_l - e_u) / ((1+e_u)(1+e_l)),  e = exp(-x) clamped finite.
__device__ __forceinline__ float sigmoid_diff(float xu, float xl) {
    float eu = __expf(fminf(-xu, 87.0f));
    float el = __expf(fminf(-xl, 87.0f));
    return __fdividef(el - eu, (1.0f + eu) * (1.0f + el));
}

__device__ __forceinline__ void accum4(
    const v4f& pf, const v4f& tf,
    const v4f& m0, const v4f& s0, const v4f& w0,
    const v4f& m1, const v4f& s1, const v4f& w1,
    const v4f& m2, const v4f& s2, const v4f& w2,
    float& bce, float& ll, float& npaid)
{
    float lik[4] = {0.0f, 0.0f, 0.0f, 0.0f};
    const v4f* mm[3] = {&m0, &m1, &m2};
    const v4f* ss[3] = {&s0, &s1, &s2};
    const v4f* ww[3] = {&w0, &w1, &w2};
    #pragma unroll
    for (int k = 0; k < 3; ++k) {
        const v4f m = *mm[k], s = *ss[k], w = *ww[k];
        #pragma unroll
        for (int j = 0; j < 4; ++j) {
            float inv_s = __fdividef(1.0f, s[j] + EPS);
            float xu = (tf[j] + HALF_BIN - m[j]) * inv_s;
            float xl = (tf[j] - HALF_BIN - m[j]) * inv_s;
            float pd = fmaxf(sigmoid_diff(xu, xl), EPS);
            lik[j] = fmaf(w[j], pd, lik[j]);
        }
    }
    #pragma unroll
    for (int j = 0; j < 4; ++j) {
        bool paid = tf[j] > 0.0f;
        float val = paid ? pf[j] : (1.0f - pf[j]);
        bce -= fmaxf(__logf(val), -100.0f);
        float lg = __logf(lik[j] + EPS);
        ll    += paid ? lg : 0.0f;
        npaid += paid ? 1.0f : 0.0f;
    }
}

// ---- K=3 fast path: forced 11-deep load batches per group ----
__global__ __launch_bounds__(256, 4) void zimol_main_k3(
    const float* __restrict__ p,
    const float* __restrict__ mu,
    const float* __restrict__ sigma,
    const float* __restrict__ weight,
    const float* __restrict__ tv,
    float* __restrict__ part_bce,
    float* __restrict__ part_ll,
    float* __restrict__ part_n,
    int B)
{
    const int tid    = blockIdx.x * blockDim.x + threadIdx.x;
    const int stride = gridDim.x * blockDim.x;
    const size_t B4  = (size_t)(B >> 2);

    const v4f* __restrict__ p4  = (const v4f*)p;
    const v4f* __restrict__ tv4 = (const v4f*)tv;
    const v4f* __restrict__ mu4 = (const v4f*)mu;
    const v4f* __restrict__ sg4 = (const v4f*)sigma;
    const v4f* __restrict__ wt4 = (const v4f*)weight;

    float bce = 0.0f, ll = 0.0f, npaid = 0.0f;

    for (size_t i = (size_t)tid; i < B4; i += (size_t)stride) {
        v4f bp, bt, bm0, bs0, bw0, bm1, bs1, bw1, bm2, bs2, bw2;
        GLOAD4(bp,  p4  + i);
        GLOAD4(bt,  tv4 + i);
        GLOAD4(bm0, mu4 + i);
        GLOAD4(bs0, sg4 + i);
        GLOAD4(bw0, wt4 + i);
        GLOAD4(bm1, mu4 + B4 + i);
        GLOAD4(bs1, sg4 + B4 + i);
        GLOAD4(bw1, wt4 + B4 + i);
        GLOAD4(bm2, mu4 + 2 * B4 + i);
        GLOAD4(bs2, sg4 + 2 * B4 + i);
        GLOAD4(bw2, wt4 + 2 * B4 + i);
        asm volatile("s_waitcnt vmcnt(0)"
                     : "+v"(bp), "+v"(bt),
                       "+v"(bm0), "+v"(bs0), "+v"(bw0),
                       "+v"(bm1), "+v"(bs1), "+v"(bw1),
                       "+v"(bm2), "+v"(bs2), "+v"(bw2));
        accum4(bp, bt, bm0, bs0, bw0, bm1, bs1, bw1, bm2, bs2, bw2,
               bce, ll, npaid);
    }

    #pragma unroll
    for (int off = 32; off > 0; off >>= 1) {
        bce   += __shfl_down(bce,   off, 64);
        ll    += __shfl_down(ll,    off, 64);
        npaid += __shfl_down(npaid, off, 64);
    }
    __shared__ float sdata[3][4];
    const int wave = threadIdx.x >> 6;
    const int lane = threadIdx.x & 63;
    if (lane == 0) {
        sdata[0][wave] = bce; sdata[1][wave] = ll; sdata[2][wave] = npaid;
    }
    __syncthreads();
    if (threadIdx.x == 0) {
        float b = 0.0f, l = 0.0f, n = 0.0f;
        #pragma unroll
        for (int w = 0; w < 4; ++w) {
            b += sdata[0][w]; l += sdata[1][w]; n += sdata[2][w];
        }
        part_bce[blockIdx.x] = b;
        part_ll [blockIdx.x] = l;
        part_n  [blockIdx.x] = n;
    }
}

// ---- generic fallback (any K, any B) ----
template <int K>
__global__ __launch_bounds__(256) void zimol_main_gen(
    const float* __restrict__ p,
    const float* __restrict__ mu,
    const float* __restrict__ sigma,
    const float* __restrict__ weight,
    const float* __restrict__ tv,
    float* __restrict__ part_bce,
    float* __restrict__ part_ll,
    float* __restrict__ part_n,
    int B)
{
    const int tid    = blockIdx.x * blockDim.x + threadIdx.x;
    const int stride = gridDim.x * blockDim.x;

    float bce = 0.0f, ll = 0.0f, npaid = 0.0f;

    for (int i = tid; i < B; i += stride) {
        float t = tv[i];
        float lik = 0.0f;
        #pragma unroll
        for (int k = 0; k < K; ++k) {
            size_t off = (size_t)k * (size_t)B + (size_t)i;
            float inv_s = __fdividef(1.0f, sigma[off] + EPS);
            float xu = (t + HALF_BIN - mu[off]) * inv_s;
            float xl = (t - HALF_BIN - mu[off]) * inv_s;
            float pd = fmaxf(sigmoid_diff(xu, xl), EPS);
            lik = fmaf(weight[off], pd, lik);
        }
        bool paid = t > 0.0f;
        float val = paid ? p[i] : (1.0f - p[i]);
        bce -= fmaxf(__logf(val), -100.0f);
        float lg = __logf(lik + EPS);
        ll    += paid ? lg : 0.0f;
        npaid += paid ? 1.0f : 0.0f;
    }

    #pragma unroll
    for (int off = 32; off > 0; off >>= 1) {
        bce   += __shfl_down(bce,   off, 64);
        ll    += __shfl_down(ll,    off, 64);
        npaid += __shfl_down(npaid, off, 64);
    }
    __shared__ float sdata[3][4];
    const int wave = threadIdx.x >> 6;
    const int lane = threadIdx.x & 63;
    if (lane == 0) {
        sdata[0][wave] = bce; sdata[1][wave] = ll; sdata[2][wave] = npaid;
    }
    __syncthreads();
    if (threadIdx.x == 0) {
        float b = 0.0f, l = 0.0f, n = 0.0f;
        #pragma unroll
        for (int w = 0; w < 4; ++w) {
            b += sdata[0][w]; l += sdata[1][w]; n += sdata[2][w];
        }
        part_bce[blockIdx.x] = b;
        part_ll [blockIdx.x] = l;
        part_n  [blockIdx.x] = n;
    }
}

__global__ __launch_bounds__(256) void zimol_reduce(
    const float* __restrict__ part_bce,
    const float* __restrict__ part_ll,
    const float* __restrict__ part_n,
    float* __restrict__ out, int nblocks, int B)
{
    double b = 0.0, l = 0.0, n = 0.0;
    for (int i = threadIdx.x; i < nblocks; i += 256) {
        b += (double)part_bce[i];
        l += (double)part_ll[i];
        n += (double)part_n[i];
    }
    #pragma unroll
    for (int off = 32; off > 0; off >>= 1) {
        b += __shfl_down(b, off, 64);
        l += __shfl_down(l, off, 64);
        n += __shfl_down(n, off, 64);
    }
    __shared__ double sdata[3][4];
    const int wave = threadIdx.x >> 6;
    const int lane = threadIdx.x & 63;
    if (lane == 0) {
        sdata[0][wave] = b; sdata[1][wave] = l; sdata[2][wave] = n;
    }
    __syncthreads();
    if (threadIdx.x == 0) {
        double tb = 0.0, tl = 0.0, tn = 0.0;
        #pragma unroll
        for (int w = 0; w < 4; ++w) {
            tb += sdata[0][w]; tl += sdata[1][w]; tn += sdata[2][w];
        }
        double purchase = tb / (double)B;
        double ltv = (tn > 0.0) ? -(tl / fmax(tn, 1.0)) : 0.0;
        out[0] = (float)(purchase + ltv);
    }
}

extern "C" void kernel_launch(void* const* d_in, const int* in_sizes, int n_in,
                              void* d_out, int out_size, void* d_ws, size_t ws_size,
                              hipStream_t stream) {
    const float* p      = (const float*)d_in[0];
    const float* mu     = (const float*)d_in[1];
    const float* sigma  = (const float*)d_in[2];
    const float* weight = (const float*)d_in[3];
    const float* tv     = (const float*)d_in[4];
    float* out = (float*)d_out;

    const int B = in_sizes[0];
    const int K = in_sizes[1] / B;

    const int threads = 256;
    int blocks;

    float* part_bce = (float*)d_ws;

    if (K == 3 && (B & 3) == 0) {
        // 2048 blocks: 2 float4-groups/thread at B=4M; each group is an
        // 11-deep forced load batch (MLP=11/wave).
        int work = B >> 2;
        blocks = (work + threads - 1) / threads;
        if (blocks > 2048) blocks = 2048;
        if (blocks < 1) blocks = 1;
        float* part_ll = part_bce + blocks;
        float* part_n  = part_ll  + blocks;
        zimol_main_k3<<<blocks, threads, 0, stream>>>(
            p, mu, sigma, weight, tv, part_bce, part_ll, part_n, B);
        zimol_reduce<<<1, threads, 0, stream>>>(part_bce, part_ll, part_n, out, blocks, B);
    } else {
        blocks = (B + threads - 1) / threads;
        if (blocks > 2048) blocks = 2048;
        if (blocks < 1) blocks = 1;
        float* part_ll = part_bce + blocks;
        float* part_n  = part_ll  + blocks;
        if (K == 1) {
            zimol_main_gen<1><<<blocks, threads, 0, stream>>>(
                p, mu, sigma, weight, tv, part_bce, part_ll, part_n, B);
        } else if (K == 2) {
            zimol_main_gen<2><<<blocks, threads, 0, stream>>>(
                p, mu, sigma, weight, tv, part_bce, part_ll, part_n, B);
        } else if (K == 3) {
            zimol_main_gen<3><<<blocks, threads, 0, stream>>>(
                p, mu, sigma, weight, tv, part_bce, part_ll, part_n, B);
        } else {
            zimol_main_gen<4><<<blocks, threads, 0, stream>>>(
                p, mu, sigma, weight, tv, part_bce, part_ll, part_n, B);
        }
        zimol_reduce<<<1, threads, 0, stream>>>(part_bce, part_ll, part_n, out, blocks, B);
    }
}